// Round 16
// baseline (173.304 us; speedup 1.0000x reference)
//
#include <hip/hip_runtime.h>
#include <hip/hip_fp16.h>
#include <math.h>

// Caps1D dynamic routing — REGISTER-resident packed-fp16 u_ji, no LDS tile.
//
// u: [B=1024, R=2336, M=4] fp32 ; W: [K=2, R=2336, M=4, P=16] fp32
// out[b,k] = norm/(1+norm) of final squashed routing sum.
//
// Design shift vs r6-r15 (LDS-resident u_ji): packed fp16 u_ji is only
// 5 rows x 8 half2 = 40 VGPRs/thread (thread-per-row, 512 thr), so it fits
// in registers WITHOUT spilling — the r1-r5 failures were 80 fp32 regs +
// working set vs 64/128 caps. Benefits: sweeps have zero LDS traffic, the
// build has 9 independent coalesced loads per row (natural MLP — replaces
// r10-r15's hand prefetch), LDS drops 76KB -> 1.1KB so occupancy is
// VGPR-bound instead of LDS-bound.
//
// W prepass layout: 8 q-planes, Wq[(k*8+q)*RR + r] = float4 of 4 half2
// {(W[m0,2q],W[m1,2q]), (W[m2,2q],W[m3,2q]), (W[m0,2q+1],W[m1,2q+1]),
//  (W[m2,2q+1],W[m3,2q+1])} -> per (j,q) lane loads are 16B contiguous
// across lanes (8 cache lines, minimal).
//
// Iteration 0 = e=1 sweep over register u_ji (after build; keeps build
// register peak low). Per iteration: 17-value 6-level xor butterfly ->
// lane-0 writes 17 floats -> 1 barrier -> distributed cross-wave squash.
// red[] double-buffered so 1 barrier/iteration is race-free.
//
// RULES (r12): per-thread arrays fully-unrolled constant-indexed,
// unconditionally initialized, no whole-array type-punning. r14: no
// sched_barrier fences. r2-r9: 512 thr + launch_bounds(512,2) = 128 cap.

#define THREADS 512
#define NWAVE 8
#define RR 2336
#define KK 2

#if __has_builtin(__builtin_amdgcn_fdot2)
typedef _Float16 h2v __attribute__((ext_vector_type(2)));
static __device__ __forceinline__ float dot2h(__half2 a, __half2 b, float c) {
    h2v av, bv;
    __builtin_memcpy(&av, &a, 4);
    __builtin_memcpy(&bv, &b, 4);
    return __builtin_amdgcn_fdot2(av, bv, c, false);
}
#else
static __device__ __forceinline__ float dot2h(__half2 a, __half2 b, float c) {
    float2 fa = __half22float2(a), fb = __half22float2(b);
    return fmaf(fa.x, fb.x, fmaf(fa.y, fb.y, c));
}
#endif

// ---- prepass: W fp32 [k][r][m][p] -> 8 q-planes of float4 records ----
__global__ __launch_bounds__(256)
void w_repack_kernel(const float* __restrict__ W, __half2* __restrict__ Wt)
{
    const int n = KK * 8 * RR;                   // 37376 records x 16 B
    for (int j = blockIdx.x * 256 + threadIdx.x; j < n; j += gridDim.x * 256) {
        const int r  = j % RR;
        const int kq = j / RR;
        const int q  = kq & 7;
        const int k  = kq >> 3;
        const float* wp = W + (size_t)(k * RR + r) * 64;   // [m][p]
        const int p0 = 2 * q, p1 = 2 * q + 1;
        __half2* o = Wt + (size_t)j * 4;
        o[0] = __floats2half2_rn(wp[0*16 + p0], wp[1*16 + p0]);
        o[1] = __floats2half2_rn(wp[2*16 + p0], wp[3*16 + p0]);
        o[2] = __floats2half2_rn(wp[0*16 + p1], wp[1*16 + p1]);
        o[3] = __floats2half2_rn(wp[2*16 + p1], wp[3*16 + p1]);
    }
}

__global__ __launch_bounds__(THREADS, 2)
void caps_routing_kernel(const float* __restrict__ u,
                         const __half2* __restrict__ Wt,
                         float* __restrict__ out)
{
    __shared__ float red[2][NWAVE][17];          // double-buffered partials

    const int bi   = blockIdx.x;                 // 2048 blocks
    const int b    = bi >> 1;
    const int k    = bi & 1;
    const int tid  = threadIdx.x;
    const int lane = tid & 63;
    const int wave = tid >> 6;

    const float4* __restrict__ u4p = (const float4*)u;
    const float4* __restrict__ wqp = (const float4*)Wt + (size_t)k * 8 * RR;

    // rows r = tid + j*512, j=0..4; j=4 valid iff tid < 288
    const bool ok4 = tid < (RR - 4 * THREADS);

    // ---- build u_ji into registers (packed fp16), 9 indep loads per row ----
    __half2 uji[5][8];
    #pragma unroll
    for (int j = 0; j < 5; ++j) {
        const int r  = tid + j * THREADS;
        const int rc = (r < RR) ? r : (RR - 1);  // clamp loads
        const bool ok = (j < 4) | ok4;
        const float4 uu = u4p[b * RR + rc];
        const __half2 u01 = __floats2half2_rn(uu.x, uu.y);
        const __half2 u23 = __floats2half2_rn(uu.z, uu.w);
        #pragma unroll
        for (int q = 0; q < 8; ++q) {
            const float4 wv = wqp[(size_t)q * RR + rc];
            const __half2* hm = (const __half2*)&wv;
            float ax = dot2h(u01, hm[0], dot2h(u23, hm[1], 0.0f));
            float ay = dot2h(u01, hm[2], dot2h(u23, hm[3], 0.0f));
            ax = ok ? ax : 0.0f;                 // invalid rows -> exact zeros
            ay = ok ? ay : 0.0f;
            uji[j][q] = __floats2half2_rn(ax, ay);
        }
    }

    float vcum_l = 0.0f;                         // lanes 0..15: cumulative v[lane]

    // ---- 3 routing iterations, all on register-resident u_ji ----
    #pragma unroll 1
    for (int it = 0; it < 3; ++it) {
        // pack cumulative v (broadcast from lanes 0..15) for the logit dot
        __half2 v2[8];
        #pragma unroll
        for (int q = 0; q < 8; ++q) {
            const float va = __shfl(vcum_l, 2 * q);
            const float vb = __shfl(vcum_l, 2 * q + 1);
            v2[q] = __floats2half2_rn(va, vb);   // zeros when it==0 (unused)
        }

        float t16[16] = {0,0,0,0,0,0,0,0,0,0,0,0,0,0,0,0};
        float se = 0.0f;
        #pragma unroll
        for (int j = 0; j < 5; ++j) {
            const bool ok = (j < 4) | ok4;
            float e;
            if (it == 0) {
                e = ok ? 1.0f : 0.0f;            // uniform softmax
            } else {
                const float d = dot2h(uji[j][0], v2[0],
                                dot2h(uji[j][1], v2[1],
                                dot2h(uji[j][2], v2[2],
                                dot2h(uji[j][3], v2[3],
                                dot2h(uji[j][4], v2[4],
                                dot2h(uji[j][5], v2[5],
                                dot2h(uji[j][6], v2[6],
                                dot2h(uji[j][7], v2[7], 0.0f))))))));
                e = ok ? __expf(d) : 0.0f;       // no max-subtract (bounded)
            }
            se += e;
            #pragma unroll
            for (int q = 0; q < 8; ++q) {
                const float2 h = __half22float2(uji[j][q]);
                t16[2*q]   = fmaf(h.x, e, t16[2*q]);
                t16[2*q+1] = fmaf(h.y, e, t16[2*q+1]);
            }
        }

        // full-wave xor butterfly: every lane ends with the wave totals
        #pragma unroll
        for (int o = 1; o <= 32; o <<= 1) {
            se += __shfl_xor(se, o);
            #pragma unroll
            for (int p = 0; p < 16; ++p) t16[p] += __shfl_xor(t16[p], o);
        }
        const int buf = it & 1;
        if (lane == 0) {
            #pragma unroll
            for (int p = 0; p < 16; ++p) red[buf][wave][p] = t16[p];
            red[buf][wave][16] = se;
        }
        __syncthreads();                         // 1 barrier per iteration

        // distributed cross-wave reduce + squash (every wave, no 2nd barrier)
        {
            float col = 0.0f;
            if (lane < 17) {
                #pragma unroll
                for (int w = 0; w < NWAVE; ++w) col += red[buf][w][lane];
            }
            float nr = col * col;                // xor net stays in 16-groups
            nr += __shfl_xor(nr, 1);
            nr += __shfl_xor(nr, 2);
            nr += __shfl_xor(nr, 4);
            nr += __shfl_xor(nr, 8);
            const float se_t = __shfl(col, 16);  // sum(e); == RR exactly at it 0
            const float inv  = 1.0f / se_t;
            const float norm = nr * inv * inv;   // |s|^2, s = col/se
            if (it < 2) {
                const float f    = sqrtf(norm) / (1.0f + norm);
                const float vnew = col * inv * f;
                if (lane < 16) vcum_l += vnew;   // cumulative V
            } else if (wave == 0 && lane == 0) {
                out[b * KK + k] = norm / (1.0f + norm);
            }
        }
    }
}

extern "C" void kernel_launch(void* const* d_in, const int* in_sizes, int n_in,
                              void* d_out, int out_size, void* d_ws, size_t ws_size,
                              hipStream_t stream) {
    const float* u = (const float*)d_in[0];   // [1024, 2336, 4]
    const float* W = (const float*)d_in[1];   // [2, 2336, 4, 16]
    float* out = (float*)d_out;               // [1024, 2]
    __half2* Wt = (__half2*)d_ws;             // 598016 B of scratch

    w_repack_kernel<<<dim3(256), dim3(256), 0, stream>>>(W, Wt);
    caps_routing_kernel<<<dim3(2048), dim3(THREADS), 0, stream>>>(u, Wt, out);
}

// Round 17
// 164.620 us; speedup vs baseline: 1.0527x; 1.0527x over previous
//
#include <hip/hip_runtime.h>
#include <hip/hip_fp16.h>
#include <math.h>

// Caps1D dynamic routing — fp16 W records, dot2 build+sweep, LDS u_ji,
// two-stream prefetch build, 768-THREAD blocks (24 waves/CU).
//
// u: [B=1024, R=2336, M=4] fp32 ; W: [K=2, R=2336, M=4, P=16] fp32
// out[b,k] = norm/(1+norm) of final squashed routing sum.
//
// Measured history: r8 W-coalescing (162->112us), r10 prefetch+dist-squash
// (->85), r11 dot2 sweep (->77), r15 two-stream named-reg prefetch (->70,
// VGPR 52, VALUBusy 51%, occupancy 38%). r16 register-resident u_ji
// REGRESSED (114us): full-wave 17x6 butterfly + per-thread 16-col FMAs ≈
// +45% VALU/iter. LDS-sweep with 2 lanes/row stays.
// r17: r15 verbatim but 768-thr blocks — LDS 76KB still fits 2 blocks/CU,
// so waves/CU 16->24; VGPR cap at (768,2) = 512/6 ≈ 84 >= the 52 this
// kernel needs (1024-thr's 64-cap poison [r2-r4,r9] avoided).
// RULES (r12): arrays fully-unrolled constant-indexed, unconditionally
// initialized, no whole-array punning. r14: no sched_barrier fences.

#define THREADS 768
#define NWAVE 12
#define RR 2336
#define KK 2

#if __has_builtin(__builtin_amdgcn_fdot2)
typedef _Float16 h2v __attribute__((ext_vector_type(2)));
static __device__ __forceinline__ float dot2h(__half2 a, __half2 b, float c) {
    h2v av, bv;
    __builtin_memcpy(&av, &a, 4);
    __builtin_memcpy(&bv, &b, 4);
    return __builtin_amdgcn_fdot2(av, bv, c, false);
}
#else
static __device__ __forceinline__ float dot2h(__half2 a, __half2 b, float c) {
    float2 fa = __half22float2(a), fb = __half22float2(b);
    return fmaf(fa.x, fb.x, fmaf(fa.y, fb.y, c));
}
#endif

// ---- prepass: W fp32 [k][r][m][p] -> records {w01x,w23x,w01y,w23y} ----
// record j = (k*RR + r)*8 + p2, 4 half2 = 16 B.
__global__ __launch_bounds__(256)
void w_repack_kernel(const float* __restrict__ W, __half2* __restrict__ Wt)
{
    const int n = KK * RR * 8;                   // 37376 records
    for (int j = blockIdx.x * 256 + threadIdx.x; j < n; j += gridDim.x * 256) {
        const int p2 = j & 7;
        const int rk = j >> 3;                   // k*RR + r
        const float* wp = W + (size_t)rk * 64;   // [m][p], 64 floats
        const float x0 = wp[0*16 + 2*p2],     x1 = wp[1*16 + 2*p2];
        const float x2 = wp[2*16 + 2*p2],     x3 = wp[3*16 + 2*p2];
        const float y0 = wp[0*16 + 2*p2 + 1], y1 = wp[1*16 + 2*p2 + 1];
        const float y2 = wp[2*16 + 2*p2 + 1], y3 = wp[3*16 + 2*p2 + 1];
        __half2* o = Wt + (size_t)j * 4;
        o[0] = __floats2half2_rn(x0, x1);
        o[1] = __floats2half2_rn(x2, x3);
        o[2] = __floats2half2_rn(y0, y1);
        o[3] = __floats2half2_rn(y2, y3);
    }
}

__global__ __launch_bounds__(THREADS, 2)
void caps_routing_kernel(const float* __restrict__ u,
                         const __half2* __restrict__ Wt,
                         float* __restrict__ out)
{
    __shared__ __half uji[RR * 16];              // 74752 B
    __shared__ float  red[2][NWAVE][17];         // double-buffered partials

    const int bi   = blockIdx.x;                 // 2048 blocks
    const int b    = bi >> 1;
    const int k    = bi & 1;
    const int tid  = threadIdx.x;
    const int lane = tid & 63;
    const int wave = tid >> 6;                   // 0..11
    const int p2   = lane & 7;                   // half2 column pair 0..7
    const int g    = lane >> 3;                  // row-in-group 0..7

    const float4* __restrict__ u4p = (const float4*)u;
    const float4* __restrict__ w4t = (const float4*)Wt + (size_t)k * RR * 8 + p2;

    // ---- build u_ji (fp16 -> LDS) + iter-0 sums; two-stream prefetch ----
    // rbase = wave*8+g in [0,96). Stream A rows [0,1152) 12 steps, stream B
    // rows [1152,2304) 12 steps, tail 2304..2335 = waves 0..3 (wave-uniform).
    float sA = 0.0f, sB = 0.0f;
    {
        const int rbase = wave * 8 + g;
        float4 uuA_n = u4p[b * RR + rbase];
        float4 wvA_n = w4t[(size_t)rbase * 8];
        float4 uuB_n = u4p[b * RR + 1152 + rbase];
        float4 wvB_n = w4t[(size_t)(1152 + rbase) * 8];
        #pragma unroll 3
        for (int i = 0; i < 12; ++i) {
            const float4 uuA = uuA_n, wvA = wvA_n;
            const float4 uuB = uuB_n, wvB = wvB_n;
            if (i + 1 < 12) {                    // prefetch both streams
                const int ra = (i + 1) * 96 + rbase;
                uuA_n = u4p[b * RR + ra];
                wvA_n = w4t[(size_t)ra * 8];
                const int rb = 1152 + (i + 1) * 96 + rbase;
                uuB_n = u4p[b * RR + rb];
                wvB_n = w4t[(size_t)rb * 8];
            }
            {   // stream A compute
                const int r = i * 96 + rbase;
                const __half2 u01 = __floats2half2_rn(uuA.x, uuA.y);
                const __half2 u23 = __floats2half2_rn(uuA.z, uuA.w);
                const __half2* hm = (const __half2*)&wvA;
                const float ax = dot2h(u01, hm[0], dot2h(u23, hm[1], 0.0f));
                const float ay = dot2h(u01, hm[2], dot2h(u23, hm[3], 0.0f));
                sA += ax; sB += ay;
                *(__half2*)(uji + r * 16 + p2 * 2) = __floats2half2_rn(ax, ay);
            }
            {   // stream B compute
                const int r = 1152 + i * 96 + rbase;
                const __half2 u01 = __floats2half2_rn(uuB.x, uuB.y);
                const __half2 u23 = __floats2half2_rn(uuB.z, uuB.w);
                const __half2* hm = (const __half2*)&wvB;
                const float ax = dot2h(u01, hm[0], dot2h(u23, hm[1], 0.0f));
                const float ay = dot2h(u01, hm[2], dot2h(u23, hm[3], 0.0f));
                sA += ax; sB += ay;
                *(__half2*)(uji + r * 16 + p2 * 2) = __floats2half2_rn(ax, ay);
            }
        }
        if (wave < 4) {                          // tail rows 2304..2335
            const int r = 2304 + rbase;
            const float4 uu = u4p[b * RR + r];
            const float4 wv = w4t[(size_t)r * 8];
            const __half2 u01 = __floats2half2_rn(uu.x, uu.y);
            const __half2 u23 = __floats2half2_rn(uu.z, uu.w);
            const __half2* hm = (const __half2*)&wv;
            const float ax = dot2h(u01, hm[0], dot2h(u23, hm[1], 0.0f));
            const float ay = dot2h(u01, hm[2], dot2h(u23, hm[3], 0.0f));
            sA += ax; sB += ay;
            *(__half2*)(uji + r * 16 + p2 * 2) = __floats2half2_rn(ax, ay);
        }
    }
    // iter-0 partials: reduce over g (xor 8/16/32 preserves p2)
    sA += __shfl_xor(sA, 8);  sB += __shfl_xor(sB, 8);
    sA += __shfl_xor(sA, 16); sB += __shfl_xor(sB, 16);
    sA += __shfl_xor(sA, 32); sB += __shfl_xor(sB, 32);
    if (lane < 8) {
        red[0][wave][2 * p2]     = sA;
        red[0][wave][2 * p2 + 1] = sB;
    }
    __syncthreads();                             // barrier 1: uji + red[0] ready

    float vcum[8];                               // this lane's v[(lane&1)*8+i]

    // ---- distributed squash, iter 0 (se == RR exactly) ----
    {
        float col = 0.0f;
        if (lane < 16) {
            #pragma unroll
            for (int w = 0; w < NWAVE; ++w) col += red[0][w][lane];
        }
        float nr = col * col;
        nr += __shfl_xor(nr, 1);
        nr += __shfl_xor(nr, 2);
        nr += __shfl_xor(nr, 4);
        nr += __shfl_xor(nr, 8);
        const float inv  = 1.0f / (float)RR;
        const float norm = nr * inv * inv;
        const float f    = sqrtf(norm) / (1.0f + norm);
        const float vnew = col * inv * f;        // valid in lanes 0..15
        #pragma unroll
        for (int i = 0; i < 8; ++i) vcum[i] = __shfl(vnew, (lane & 1) * 8 + i);
    }

    // ---- iterations 1,2: sweep + distributed squash ----
    // rows: s*384 + wave*32 + (lane>>1), s in [0,7); clamp + ok mask.
    #pragma unroll 1
    for (int it = 1; it < 3; ++it) {
        const int buf = it & 1;

        __half2 v2[4];
        #pragma unroll
        for (int i = 0; i < 4; ++i) v2[i] = __floats2half2_rn(vcum[2*i], vcum[2*i+1]);

        // issue all 7 row-loads up front, clamped + unconditional
        float4 raw[7];
        #pragma unroll
        for (int s = 0; s < 7; ++s) {
            int row = s * 384 + wave * 32 + (lane >> 1);
            row = (row < RR) ? row : (RR - 1);
            raw[s] = *(const float4*)((const char*)uji + row * 32 + (lane & 1) * 16);
        }

        float s8[8] = {0,0,0,0,0,0,0,0};
        float se = 0.0f;
        #pragma unroll
        for (int s = 0; s < 7; ++s) {
            const bool ok = (s * 384 + wave * 32 + (lane >> 1)) < RR;
            const __half2* hp = (const __half2*)&raw[s];
            float d = dot2h(hp[0], v2[0],
                      dot2h(hp[1], v2[1],
                      dot2h(hp[2], v2[2],
                      dot2h(hp[3], v2[3], 0.0f))));
            d += __shfl_xor(d, 1);               // join the two half-dots
            float e = ok ? __expf(d) : 0.0f;     // no max-subtract (bounded)
            se += e;
            #pragma unroll
            for (int q = 0; q < 4; ++q) {
                float2 f = __half22float2(hp[q]);
                s8[2*q]   = fmaf(f.x, e, s8[2*q]);
                s8[2*q+1] = fmaf(f.y, e, s8[2*q+1]);
            }
        }

        // parity-preserving xor reduction (offsets 2..32 keep lane bit0)
        #pragma unroll
        for (int o = 2; o <= 32; o <<= 1) {
            se += __shfl_xor(se, o);
            #pragma unroll
            for (int i = 0; i < 8; ++i) s8[i] += __shfl_xor(s8[i], o);
        }
        if (lane < 2) {
            #pragma unroll
            for (int i = 0; i < 8; ++i) red[buf][wave][(lane & 1) * 8 + i] = s8[i];
            if (lane == 0) red[buf][wave][16] = se;
        }
        __syncthreads();                         // barrier 2 / 3

        // distributed squash from red[buf]
        {
            float col = 0.0f;
            if (lane < 17) {
                #pragma unroll
                for (int w = 0; w < NWAVE; ++w) col += red[buf][w][lane];
            }
            float nr = col * col;
            nr += __shfl_xor(nr, 1);
            nr += __shfl_xor(nr, 2);
            nr += __shfl_xor(nr, 4);
            nr += __shfl_xor(nr, 8);
            const float se_t = __shfl(col, 16);  // lane 16 carried sum(e)
            const float inv  = 1.0f / se_t;
            const float norm = nr * inv * inv;
            if (it == 1) {
                const float f    = sqrtf(norm) / (1.0f + norm);
                const float vnew = col * inv * f;
                #pragma unroll
                for (int i = 0; i < 8; ++i) vcum[i] += __shfl(vnew, (lane & 1) * 8 + i);
            } else if (wave == 0 && lane == 0) {
                out[b * KK + k] = norm / (1.0f + norm);
            }
        }
    }
}

extern "C" void kernel_launch(void* const* d_in, const int* in_sizes, int n_in,
                              void* d_out, int out_size, void* d_ws, size_t ws_size,
                              hipStream_t stream) {
    const float* u = (const float*)d_in[0];   // [1024, 2336, 4]
    const float* W = (const float*)d_in[1];   // [2, 2336, 4, 16]
    float* out = (float*)d_out;               // [1024, 2]
    __half2* Wt = (__half2*)d_ws;             // 299008 B of scratch

    w_repack_kernel<<<dim3(256), dim3(256), 0, stream>>>(W, Wt);
    caps_routing_kernel<<<dim3(2048), dim3(THREADS), 0, stream>>>(u, Wt, out);
}

// Round 18
// 128.358 us; speedup vs baseline: 1.3502x; 1.2825x over previous
//
#include <hip/hip_runtime.h>
#include <hip/hip_fp16.h>
#include <math.h>

// Caps1D dynamic routing — fp16 W records, dot2 build+sweep, LDS u_ji,
// THREE-STREAM named-register prefetch build (6 loads in flight).
//
// u: [B=1024, R=2336, M=4] fp32 ; W: [K=2, R=2336, M=4, P=16] fp32
// out[b,k] = norm/(1+norm) of final squashed routing sum.
//
// Measured history: r8 W-coalescing (162->112us steady), r10 depth-1
// named-reg prefetch + distributed squash (->85), r11 dot2 sweep (->77),
// r15 two-stream prefetch (->70; VGPR 52, VALUBusy 51%, occ 38%).
// FAILED branches (all measured): 1024-thr blocks (64-VGPR hard cap: r2-4,
// r9), 768-thr blocks (r17: compiler drops to VGPR 44, occ 33%, 107us),
// register-resident u_ji (r16: +45% VALU/iter, 114us), sched_barrier
// fences (r14: occ 40->21%, 105us), array-chunk pipelines (r11 sunk /
// r12 scratch-homed 287MB). The ONLY reliably-winning lever: deeper
// named-scalar prefetch. r18 = r15 + third stream.
// RULES (r12): arrays fully-unrolled constant-indexed, unconditionally
// initialized, no whole-array punning. 512 thr + launch_bounds(512,2).

#define THREADS 512
#define NWAVE 8
#define RR 2336
#define KK 2

#if __has_builtin(__builtin_amdgcn_fdot2)
typedef _Float16 h2v __attribute__((ext_vector_type(2)));
static __device__ __forceinline__ float dot2h(__half2 a, __half2 b, float c) {
    h2v av, bv;
    __builtin_memcpy(&av, &a, 4);
    __builtin_memcpy(&bv, &b, 4);
    return __builtin_amdgcn_fdot2(av, bv, c, false);
}
#else
static __device__ __forceinline__ float dot2h(__half2 a, __half2 b, float c) {
    float2 fa = __half22float2(a), fb = __half22float2(b);
    return fmaf(fa.x, fb.x, fmaf(fa.y, fb.y, c));
}
#endif

// ---- prepass: W fp32 [k][r][m][p] -> records {w01x,w23x,w01y,w23y} ----
// record j = (k*RR + r)*8 + p2, 4 half2 = 16 B.
__global__ __launch_bounds__(256)
void w_repack_kernel(const float* __restrict__ W, __half2* __restrict__ Wt)
{
    const int n = KK * RR * 8;                   // 37376 records
    for (int j = blockIdx.x * 256 + threadIdx.x; j < n; j += gridDim.x * 256) {
        const int p2 = j & 7;
        const int rk = j >> 3;                   // k*RR + r
        const float* wp = W + (size_t)rk * 64;   // [m][p], 64 floats
        const float x0 = wp[0*16 + 2*p2],     x1 = wp[1*16 + 2*p2];
        const float x2 = wp[2*16 + 2*p2],     x3 = wp[3*16 + 2*p2];
        const float y0 = wp[0*16 + 2*p2 + 1], y1 = wp[1*16 + 2*p2 + 1];
        const float y2 = wp[2*16 + 2*p2 + 1], y3 = wp[3*16 + 2*p2 + 1];
        __half2* o = Wt + (size_t)j * 4;
        o[0] = __floats2half2_rn(x0, x1);
        o[1] = __floats2half2_rn(x2, x3);
        o[2] = __floats2half2_rn(y0, y1);
        o[3] = __floats2half2_rn(y2, y3);
    }
}

// one stream's compute step (named scalars only)
#define STREAM_COMP(base, i, uu, wv)                                   \
    {                                                                  \
        const int r = (base) + (i) * 64 + rbase;                       \
        const __half2 u01 = __floats2half2_rn(uu.x, uu.y);             \
        const __half2 u23 = __floats2half2_rn(uu.z, uu.w);             \
        const __half2* hm = (const __half2*)&wv;                       \
        const float ax = dot2h(u01, hm[0], dot2h(u23, hm[1], 0.0f));   \
        const float ay = dot2h(u01, hm[2], dot2h(u23, hm[3], 0.0f));   \
        sA += ax; sB += ay;                                            \
        *(__half2*)(uji + r * 16 + p2 * 2) = __floats2half2_rn(ax, ay); \
    }

__global__ __launch_bounds__(THREADS, 2)
void caps_routing_kernel(const float* __restrict__ u,
                         const __half2* __restrict__ Wt,
                         float* __restrict__ out)
{
    __shared__ __half uji[RR * 16];              // 74752 B
    __shared__ float  red[2][NWAVE][17];         // double-buffered partials

    const int bi   = blockIdx.x;                 // 2048 blocks
    const int b    = bi >> 1;
    const int k    = bi & 1;
    const int tid  = threadIdx.x;
    const int lane = tid & 63;
    const int wave = tid >> 6;
    const int p2   = lane & 7;                   // half2 column pair 0..7
    const int g    = lane >> 3;                  // row-in-group 0..7

    const float4* __restrict__ u4p = (const float4*)u;
    const float4* __restrict__ w4t = (const float4*)Wt + (size_t)k * RR * 8 + p2;

    // ---- build u_ji (fp16 -> LDS) + iter-0 sums; THREE-stream prefetch ----
    // streams A/B/C rows [0,768)/[768,1536)/[1536,2304), 12 steps each,
    // guard-free; tail rows 2304..2335 = waves 0..3 (wave-uniform).
    float sA = 0.0f, sB = 0.0f;
    {
        const int rbase = wave * 8 + g;
        float4 uuA_n = u4p[b * RR + rbase];
        float4 wvA_n = w4t[(size_t)rbase * 8];
        float4 uuB_n = u4p[b * RR + 768 + rbase];
        float4 wvB_n = w4t[(size_t)(768 + rbase) * 8];
        float4 uuC_n = u4p[b * RR + 1536 + rbase];
        float4 wvC_n = w4t[(size_t)(1536 + rbase) * 8];
        #pragma unroll 3
        for (int i = 0; i < 12; ++i) {
            const float4 uuA = uuA_n, wvA = wvA_n;
            const float4 uuB = uuB_n, wvB = wvB_n;
            const float4 uuC = uuC_n, wvC = wvC_n;
            if (i + 1 < 12) {                    // prefetch all three streams
                const int ra = (i + 1) * 64 + rbase;
                uuA_n = u4p[b * RR + ra];
                wvA_n = w4t[(size_t)ra * 8];
                const int rb = 768 + (i + 1) * 64 + rbase;
                uuB_n = u4p[b * RR + rb];
                wvB_n = w4t[(size_t)rb * 8];
                const int rc = 1536 + (i + 1) * 64 + rbase;
                uuC_n = u4p[b * RR + rc];
                wvC_n = w4t[(size_t)rc * 8];
            }
            STREAM_COMP(0,    i, uuA, wvA)
            STREAM_COMP(768,  i, uuB, wvB)
            STREAM_COMP(1536, i, uuC, wvC)
        }
        if (wave < 4) {                          // tail rows 2304..2335
            const int r = 2304 + rbase;
            const float4 uu = u4p[b * RR + r];
            const float4 wv = w4t[(size_t)r * 8];
            const __half2 u01 = __floats2half2_rn(uu.x, uu.y);
            const __half2 u23 = __floats2half2_rn(uu.z, uu.w);
            const __half2* hm = (const __half2*)&wv;
            const float ax = dot2h(u01, hm[0], dot2h(u23, hm[1], 0.0f));
            const float ay = dot2h(u01, hm[2], dot2h(u23, hm[3], 0.0f));
            sA += ax; sB += ay;
            *(__half2*)(uji + r * 16 + p2 * 2) = __floats2half2_rn(ax, ay);
        }
    }
    // iter-0 partials: reduce over g (xor 8/16/32 preserves p2)
    sA += __shfl_xor(sA, 8);  sB += __shfl_xor(sB, 8);
    sA += __shfl_xor(sA, 16); sB += __shfl_xor(sB, 16);
    sA += __shfl_xor(sA, 32); sB += __shfl_xor(sB, 32);
    if (lane < 8) {
        red[0][wave][2 * p2]     = sA;
        red[0][wave][2 * p2 + 1] = sB;
    }
    __syncthreads();                             // barrier 1: uji + red[0] ready

    float vcum[8];                               // this lane's v[(lane&1)*8+i]

    // ---- distributed squash, iter 0 (se == RR exactly) ----
    {
        float col = 0.0f;
        if (lane < 16) {
            #pragma unroll
            for (int w = 0; w < NWAVE; ++w) col += red[0][w][lane];
        }
        float nr = col * col;
        nr += __shfl_xor(nr, 1);
        nr += __shfl_xor(nr, 2);
        nr += __shfl_xor(nr, 4);
        nr += __shfl_xor(nr, 8);
        const float inv  = 1.0f / (float)RR;
        const float norm = nr * inv * inv;
        const float f    = sqrtf(norm) / (1.0f + norm);
        const float vnew = col * inv * f;        // valid in lanes 0..15
        #pragma unroll
        for (int i = 0; i < 8; ++i) vcum[i] = __shfl(vnew, (lane & 1) * 8 + i);
    }

    // ---- iterations 1,2: sweep + distributed squash (r15 form, verbatim) ----
    #pragma unroll 1
    for (int it = 1; it < 3; ++it) {
        const int buf = it & 1;

        __half2 v2[4];
        #pragma unroll
        for (int i = 0; i < 4; ++i) v2[i] = __floats2half2_rn(vcum[2*i], vcum[2*i+1]);

        // issue all 10 row-loads up front, clamped + unconditional
        float4 raw[10];
        #pragma unroll
        for (int s = 0; s < 10; ++s) {
            int row = s * 256 + wave * 32 + (lane >> 1);
            row = (row < RR) ? row : (RR - 1);
            raw[s] = *(const float4*)((const char*)uji + row * 32 + (lane & 1) * 16);
        }

        float s8[8] = {0,0,0,0,0,0,0,0};
        float se = 0.0f;
        #pragma unroll
        for (int s = 0; s < 10; ++s) {
            const bool ok = (s * 256 + wave * 32 + (lane >> 1)) < RR;
            const __half2* hp = (const __half2*)&raw[s];
            float d = dot2h(hp[0], v2[0],
                      dot2h(hp[1], v2[1],
                      dot2h(hp[2], v2[2],
                      dot2h(hp[3], v2[3], 0.0f))));
            d += __shfl_xor(d, 1);               // join the two half-dots
            float e = ok ? __expf(d) : 0.0f;     // no max-subtract (bounded)
            se += e;
            #pragma unroll
            for (int q = 0; q < 4; ++q) {
                float2 f = __half22float2(hp[q]);
                s8[2*q]   = fmaf(f.x, e, s8[2*q]);
                s8[2*q+1] = fmaf(f.y, e, s8[2*q+1]);
            }
        }

        // parity-preserving xor reduction (offsets 2..32 keep lane bit0)
        #pragma unroll
        for (int o = 2; o <= 32; o <<= 1) {
            se += __shfl_xor(se, o);
            #pragma unroll
            for (int i = 0; i < 8; ++i) s8[i] += __shfl_xor(s8[i], o);
        }
        if (lane < 2) {
            #pragma unroll
            for (int i = 0; i < 8; ++i) red[buf][wave][(lane & 1) * 8 + i] = s8[i];
            if (lane == 0) red[buf][wave][16] = se;
        }
        __syncthreads();                         // barrier 2 / 3

        // distributed squash from red[buf]
        {
            float col = 0.0f;
            if (lane < 17) {
                #pragma unroll
                for (int w = 0; w < NWAVE; ++w) col += red[buf][w][lane];
            }
            float nr = col * col;
            nr += __shfl_xor(nr, 1);
            nr += __shfl_xor(nr, 2);
            nr += __shfl_xor(nr, 4);
            nr += __shfl_xor(nr, 8);
            const float se_t = __shfl(col, 16);  // lane 16 carried sum(e)
            const float inv  = 1.0f / se_t;
            const float norm = nr * inv * inv;
            if (it == 1) {
                const float f    = sqrtf(norm) / (1.0f + norm);
                const float vnew = col * inv * f;
                #pragma unroll
                for (int i = 0; i < 8; ++i) vcum[i] += __shfl(vnew, (lane & 1) * 8 + i);
            } else if (wave == 0 && lane == 0) {
                out[b * KK + k] = norm / (1.0f + norm);
            }
        }
    }
}

extern "C" void kernel_launch(void* const* d_in, const int* in_sizes, int n_in,
                              void* d_out, int out_size, void* d_ws, size_t ws_size,
                              hipStream_t stream) {
    const float* u = (const float*)d_in[0];   // [1024, 2336, 4]
    const float* W = (const float*)d_in[1];   // [2, 2336, 4, 16]
    float* out = (float*)d_out;               // [1024, 2]
    __half2* Wt = (__half2*)d_ws;             // 299008 B of scratch

    w_repack_kernel<<<dim3(256), dim3(256), 0, stream>>>(W, Wt);
    caps_routing_kernel<<<dim3(2048), dim3(THREADS), 0, stream>>>(u, Wt, out);
}